// Round 7
// baseline (305.403 us; speedup 1.0000x reference)
//
#include <hip/hip_runtime.h>
#include <hip/hip_bf16.h>

#define TSEQ 2048
#define TBZ  32
#define TDIM 1024
#define NLS  8

typedef __attribute__((ext_vector_type(8))) short bf16x8;
typedef __attribute__((ext_vector_type(4))) float f32x4;

__device__ inline unsigned int pk2(float lo, float hi) {
    __hip_bfloat162 h = __float22bfloat162_rn(make_float2(lo, hi)); // v_cvt_pk_bf16_f32
    return *reinterpret_cast<const unsigned int*>(&h);
}

__device__ inline void gload_lds16(const void* g, void* l) {
    __builtin_amdgcn_global_load_lds(
        (const __attribute__((address_space(1))) unsigned int*)g,
        (__attribute__((address_space(3))) unsigned int*)l,
        16, 0, 0);
}

// ---------- pass 1: W f32 -> bf16 (32 MB read, ~8 us) ----------
__global__ __launch_bounds__(256) void conv_w(const float* __restrict__ W,
                                              unsigned short* __restrict__ wb) {
    const int total = NLS * TDIM * TDIM / 8;
    const int stride = gridDim.x * 256;
    for (int i = blockIdx.x * 256 + threadIdx.x; i < total; i += stride) {
        const float* src = W + (long)i * 8;
        f32x4 v0 = *(const f32x4*)(src);
        f32x4 v1 = *(const f32x4*)(src + 4);
        uint4 o;
        o.x = pk2(v0.x, v0.y); o.y = pk2(v0.z, v0.w);
        o.z = pk2(v1.x, v1.y); o.w = pk2(v1.z, v1.w);
        *(uint4*)(wb + (long)i * 8) = o;
    }
}

// ---------- pass 2: fused-A persistent 256x256 8-phase bf16 GEMM ----------
// Schedule/swizzle/reads/MFMA identical to rounds 4-6 (verified). A staging
// replaced by reg path (x f32 -> cvt_pk -> ds_write to the SAME linear LDS
// bytes): ISSUE 8 f32x4 @P1/P5, counted-vmcnt COMMIT @P3/P4/P7/P8.
// Queue invariant at each wait (steady state, per wave, in-order):
//   P3: [Bprev(4), A(8)]      -> vmcnt(4) drains Bprev + A-mh0
//   P4: [A-mh1(4), B(2)]      -> vmcnt(2) drains A-mh1
//   P7/P8 symmetric. Epilogue stores only ADD to the drained prefix (safe).
// Writer visibility: commit ds_writes drain at the writer's next LGKM(0),
// >=2 barriers before any consumer read.

#define BAR __builtin_amdgcn_s_barrier()
#define LGKM asm volatile("s_waitcnt lgkmcnt(0)" ::: "memory")
#define VMC(n) asm volatile("s_waitcnt vmcnt(" #n ")" ::: "memory")
#define FENCE asm volatile("" ::: "memory")
#define KBo(kv) ((kv) & 1023)

__global__ __launch_bounds__(512, 2) void mapper_gemm8f(
    const float* __restrict__ x,                // [s][b][d] f32
    const int* __restrict__ lang_ids,
    const unsigned short* __restrict__ wb,      // [e][out][in] bf16
    const float* __restrict__ bias,
    float* __restrict__ out)
{
    // XCD-chunked bijective swizzle: 512 = 8 * 64; nt fastest.
    const int p  = blockIdx.x;
    const int l  = (p & 7) * 64 + (p >> 3);
    const int b  = l >> 4;
    const int strip = (l >> 2) & 3;             // 2 m-tiles per strip
    const int nt = l & 3;
    const int s0 = strip * 512;
    const int e0 = nt * 256;
    const int tid = threadIdx.x;

    const int gid = 8 - lang_ids[b];
    if (!(gid >= 1 && gid <= 8)) {
        // passthrough: out[s0..s0+512][b][e0..e0+256] = x[...]
        const f32x4* xs = (const f32x4*)x;
        f32x4*       os = (f32x4*)out;
        const int rs4 = TBZ * TDIM / 4;
        for (int i = tid; i < 512 * 256 / 4; i += 512) {
            int r = i >> 6;
            int c = i & 63;
            long idx = (long)(s0 + r) * rs4 + b * (TDIM / 4) + (e0 >> 2) + c;
            os[idx] = xs[idx];
        }
        return;
    }
    const int eb = gid - 1;

    __shared__ uint4 ldsbuf[131072 / 16];
    char* ldsc = (char*)ldsbuf;

    const int lane = tid & 63;
    const int wave = tid >> 6;
    const int wr   = wave >> 2;
    const int wc   = wave & 3;
    const int fr   = lane & 15;
    const int fq   = lane >> 4;
    const int fr7  = fr & 7;

    const unsigned short* __restrict__ Bbb = wb + (long)eb * TDIM * TDIM + (long)e0 * TDIM;

    const int L    = lane;
    const int lch8 = ((L & 7) ^ (L >> 3)) * 8;   // pre-inverse-swizzled chunk (elem idx)
    const int ldA0 = wave * 2048 + L * 16;
    // A global rows (f32 x, [s][b][d]): region-local q -> global row
    //   g(q) = (q>>6)*128 + mh*64 + (q&63), q = wave*16 + j*8 + (L>>3)
    int sRowA[2];
    const unsigned short* bG[2][2];
    #pragma unroll
    for (int j = 0; j < 2; ++j) {
        const int rr = wave * 16 + j * 8 + (L >> 3);
        sRowA[j] = s0 + (rr >> 6) * 128 + (rr & 63);
        #pragma unroll
        for (int nh = 0; nh < 2; ++nh)
            bG[j][nh] = Bbb + ((rr >> 5) * 64 + nh * 32 + (rr & 31)) * TDIM + lch8;
    }

#define ISSUE_A(kv) do { \
    const int kvc_ = ((kv) < 2048) ? (kv) : 0; \
    const int radv_ = (kvc_ >> 10) << 8; \
    const int kof_ = (kvc_ & 1023); \
    _Pragma("unroll") for (int j = 0; j < 2; ++j) { \
        const float* s_ = x + (long)(sRowA[j] + radv_) * (TBZ * TDIM) + b * TDIM + kof_ + lch8; \
        ar[j*2+0] = *(const f32x4*)(s_); \
        ar[j*2+1] = *(const f32x4*)(s_ + 4); \
    } \
    FENCE; \
    _Pragma("unroll") for (int j = 0; j < 2; ++j) { \
        const float* s_ = x + (long)(sRowA[j] + radv_ + 64) * (TBZ * TDIM) + b * TDIM + kof_ + lch8; \
        ar[4+j*2+0] = *(const f32x4*)(s_); \
        ar[4+j*2+1] = *(const f32x4*)(s_ + 4); \
    } \
} while (0)

#define COMMIT_A(slot, mh) do { \
    _Pragma("unroll") for (int j = 0; j < 2; ++j) { \
        f32x4 p0_ = ar[(mh)*4 + j*2], p1_ = ar[(mh)*4 + j*2 + 1]; \
        uint4 w_; \
        w_.x = pk2(p0_.x, p0_.y); w_.y = pk2(p0_.z, p0_.w); \
        w_.z = pk2(p1_.x, p1_.y); w_.w = pk2(p1_.z, p1_.w); \
        *(uint4*)(ldsc + (slot)*32768 + (mh)*16384 + ldA0 + j*1024) = w_; \
    } \
} while (0)

#define STAGE_B(slot, nh, kofs) do { \
    gload_lds16(bG[0][nh] + (kofs), ldsc + 65536 + (slot)*32768 + (nh)*16384 + ldA0); \
    gload_lds16(bG[1][nh] + (kofs), ldsc + 65536 + (slot)*32768 + (nh)*16384 + ldA0 + 1024); \
} while (0)
#define RD_A(slot, mh) do { \
    _Pragma("unroll") for (int ml = 0; ml < 4; ++ml) { \
        const int rr = wr * 64 + ml * 16 + fr; \
        _Pragma("unroll") for (int kk = 0; kk < 2; ++kk) \
            af[ml][kk] = *(const bf16x8*)(ldsc + (slot)*32768 + (mh)*16384 + rr*128 + (((kk*4+fq) ^ fr7) << 4)); \
    } } while (0)
#define RD_B(slot, nh, br) do { \
    _Pragma("unroll") for (int nl = 0; nl < 2; ++nl) { \
        const int rr = wc * 32 + nl * 16 + fr; \
        _Pragma("unroll") for (int kk = 0; kk < 2; ++kk) \
            br[nl][kk] = *(const bf16x8*)(ldsc + 65536 + (slot)*32768 + (nh)*16384 + rr*128 + (((kk*4+fq) ^ fr7) << 4)); \
    } } while (0)
// Swapped operands (C^T): col=lane&15 -> s_local, row=(lane>>4)*4+j -> e_local.
#define MM(mh, nh, br) do { \
    __builtin_amdgcn_s_setprio(1); \
    _Pragma("unroll") for (int ml = 0; ml < 4; ++ml) \
    _Pragma("unroll") for (int nl = 0; nl < 2; ++nl) \
    _Pragma("unroll") for (int kk = 0; kk < 2; ++kk) \
        acc[(mh)*4+ml][(nh)*2+nl] = __builtin_amdgcn_mfma_f32_16x16x32_bf16( \
            br[nl][kk], af[ml][kk], acc[(mh)*4+ml][(nh)*2+nl], 0, 0, 0); \
    __builtin_amdgcn_s_setprio(0); \
} while (0)

    f32x4 acc[8][4];
    #pragma unroll
    for (int m = 0; m < 8; ++m)
        #pragma unroll
        for (int n = 0; n < 4; ++n)
            acc[m][n] = (f32x4){0.f, 0.f, 0.f, 0.f};

    f32x4  ar[8];
    bf16x8 af[4][2], bf0[2][2], bf1[2][2];

    // prologue: A(t0) -> slot0, A(t1) -> slot1 (reg array reused), B both tiles
    ISSUE_A(0);
    FENCE;
    STAGE_B(0, 0, 0); STAGE_B(0, 1, 0); STAGE_B(1, 0, 64); STAGE_B(1, 1, 64);
    VMC(8);                    // queue [A(8), B(8)] -> A(t0) done
    COMMIT_A(0, 0); COMMIT_A(0, 1);
    ISSUE_A(64);
    VMC(0);                    // drain A(t1) + all B
    COMMIT_A(1, 0); COMMIT_A(1, 1);
    LGKM; BAR;

    const int cs  = lane & 15;          // s_local
    const int eqb = (lane >> 4) << 2;   // e_local base (4 consecutive)

    for (int mtl = 0; mtl < 2; ++mtl) {
        for (int it = 0; it < 8; ++it) {
            const int kva = mtl * 1024 + it * 128;
            const int kn = kva + 128;   // tile ta+2 (slot0); wraps to next m-tile
            const int km = kva + 192;   // tile tb+2 (slot1)
            // P1
            RD_A(0, 0); RD_B(0, 0, bf0); ISSUE_A(kn);
            BAR; LGKM; MM(0, 0, bf0); BAR;
            // P2
            RD_B(0, 1, bf1);
            BAR; LGKM; MM(0, 1, bf1); BAR;
            // P3
            RD_A(0, 1); VMC(4); COMMIT_A(0, 0); STAGE_B(0, 0, KBo(kn));
            BAR; LGKM; MM(1, 0, bf0); BAR;
            // P4
            VMC(2); COMMIT_A(0, 1); STAGE_B(0, 1, KBo(kn));
            BAR; MM(1, 1, bf1); BAR;
            // P5
            RD_A(1, 0); RD_B(1, 0, bf0); ISSUE_A(km);
            BAR; LGKM; MM(0, 0, bf0); BAR;
            // P6
            RD_B(1, 1, bf1);
            BAR; LGKM; MM(0, 1, bf1); BAR;
            // P7
            RD_A(1, 1); VMC(4); COMMIT_A(1, 0); STAGE_B(1, 0, KBo(km));
            BAR; LGKM; MM(1, 0, bf0); BAR;
            // P8
            VMC(2); COMMIT_A(1, 1); STAGE_B(1, 1, KBo(km));
            BAR; MM(1, 1, bf1); BAR;
        }

        // epilogue: 32 dwordx4 stores; they only extend the drained prefix
        // of later counted waits (in-order vmcnt) -> safe
        const int sb = s0 + mtl * 256 + wr * 128;
        #pragma unroll
        for (int n = 0; n < 4; ++n) {
            const int e = e0 + wc * 64 + n * 16 + eqb;
            const f32x4 bv4 = *(const f32x4*)&bias[eb * TDIM + e];
            #pragma unroll
            for (int m = 0; m < 8; ++m) {
                const int s = sb + m * 16 + cs;
                *(f32x4*)&out[(long)s * (TBZ * TDIM) + b * TDIM + e] = acc[m][n] + bv4;
            }
        }
        #pragma unroll
        for (int m = 0; m < 8; ++m)
            #pragma unroll
            for (int n = 0; n < 4; ++n)
                acc[m][n] = (f32x4){0.f, 0.f, 0.f, 0.f};
    }
#undef ISSUE_A
#undef COMMIT_A
#undef STAGE_B
#undef RD_A
#undef RD_B
#undef MM
}

// ---------- fallback: round-1 fused kernel ----------
__device__ inline unsigned short f2bf(float f) {
    union { float f; unsigned int u; } v; v.f = f;
    unsigned int r = v.u + 0x7fffu + ((v.u >> 16) & 1u);
    return (unsigned short)(r >> 16);
}
constexpr int FLDS = 40;

__global__ __launch_bounds__(256) void mapper_fused(
    const float* __restrict__ x, const int* __restrict__ lang_ids,
    const float* __restrict__ W, const float* __restrict__ bias,
    float* __restrict__ out)
{
    const int bid = blockIdx.x;
    const int b   = bid >> 7;
    const int t   = bid & 127;
    const int mt  = t >> 3;
    const int nt  = t & 7;
    const int s0  = mt * 128;
    const int e0  = nt * 128;
    const int tid = threadIdx.x;

    const int gid = 8 - lang_ids[b];
    const bool active = (gid >= 1) && (gid <= 8);
    int eb = gid - 1; eb = eb < 0 ? 0 : (eb > 7 ? 7 : eb);

    if (!active) {
        const f32x4* xs = (const f32x4*)x;
        f32x4*       os = (f32x4*)out;
        const int rs4 = TBZ * TDIM / 4;
        for (int i = tid; i < 128 * 128 / 4; i += 256) {
            int r = i >> 5, c = i & 31;
            long idx = (long)(s0 + r) * rs4 + b * (TDIM / 4) + (e0 >> 2) + c;
            os[idx] = xs[idx];
        }
        return;
    }

    __shared__ unsigned short As[128 * FLDS];
    __shared__ unsigned short Bs[128 * FLDS];
    const float* __restrict__ Wb = W + (long)eb * TDIM * TDIM;

    const int lane = tid & 63;
    const int wave = tid >> 6;
    const int wrr  = wave >> 1;
    const int wcc  = wave & 1;

    f32x4 acc[4][4];
    #pragma unroll
    for (int m = 0; m < 4; ++m)
        #pragma unroll
        for (int n = 0; n < 4; ++n)
            acc[m][n] = (f32x4){0.f, 0.f, 0.f, 0.f};

    const int rg = tid >> 3;
    const int cg = tid & 7;
    const int fr = lane & 15;
    const int fo = (lane >> 4) * 8;

    for (int k0 = 0; k0 < TDIM; k0 += 32) {
        __syncthreads();
        #pragma unroll
        for (int pp = 0; pp < 4; ++pp) {
            const int r = rg + pp * 32;
            f32x4 av = *(const f32x4*)(x  + (long)(s0 + r) * (TBZ * TDIM) + b * TDIM + k0 + cg * 4);
            f32x4 bv = *(const f32x4*)(Wb + (long)(e0 + r) * TDIM + k0 + cg * 4);
            unsigned int alo = (unsigned)f2bf(av.x) | ((unsigned)f2bf(av.y) << 16);
            unsigned int ahi = (unsigned)f2bf(av.z) | ((unsigned)f2bf(av.w) << 16);
            unsigned int blo = (unsigned)f2bf(bv.x) | ((unsigned)f2bf(bv.y) << 16);
            unsigned int bhi = (unsigned)f2bf(bv.z) | ((unsigned)f2bf(bv.w) << 16);
            *(uint2*)&As[r * FLDS + cg * 4] = make_uint2(alo, ahi);
            *(uint2*)&Bs[r * FLDS + cg * 4] = make_uint2(blo, bhi);
        }
        __syncthreads();

        bf16x8 af2[4], bfm[4];
        #pragma unroll
        for (int m = 0; m < 4; ++m)
            af2[m] = *(const bf16x8*)&As[(wrr * 64 + m * 16 + fr) * FLDS + fo];
        #pragma unroll
        for (int n = 0; n < 4; ++n)
            bfm[n] = *(const bf16x8*)&Bs[(wcc * 64 + n * 16 + fr) * FLDS + fo];
        #pragma unroll
        for (int m = 0; m < 4; ++m)
            #pragma unroll
            for (int n = 0; n < 4; ++n)
                acc[m][n] = __builtin_amdgcn_mfma_f32_16x16x32_bf16(af2[m], bfm[n], acc[m][n], 0, 0, 0);
    }

    const int cr = lane >> 4;
    const int cc2 = lane & 15;
    #pragma unroll
    for (int n = 0; n < 4; ++n) {
        const int e  = e0 + wcc * 64 + n * 16 + cc2;
        const float bv = bias[eb * TDIM + e];
        #pragma unroll
        for (int m = 0; m < 4; ++m) {
            #pragma unroll
            for (int j = 0; j < 4; ++j) {
                const int s = s0 + wrr * 64 + m * 16 + cr * 4 + j;
                out[(long)s * (TBZ * TDIM) + b * TDIM + e] = acc[m][n][j] + bv;
            }
        }
    }
}

extern "C" void kernel_launch(void* const* d_in, const int* in_sizes, int n_in,
                              void* d_out, int out_size, void* d_ws, size_t ws_size,
                              hipStream_t stream) {
    const float* x        = (const float*)d_in[0];
    const int*   lang_ids = (const int*)d_in[1];
    const float* W        = (const float*)d_in[2];
    const float* bias     = (const float*)d_in[3];
    float*       out      = (float*)d_out;

    const size_t wbytes = (size_t)NLS * TDIM * TDIM * 2;   // 16 MiB

    if (ws_size >= wbytes) {
        unsigned short* wbp = (unsigned short*)d_ws;
        conv_w<<<2048, 256, 0, stream>>>(W, wbp);
        mapper_gemm8f<<<512, 512, 0, stream>>>(x, lang_ids, wbp, bias, out);
    } else {
        mapper_fused<<<TBZ * 16 * 8, 256, 0, stream>>>(x, lang_ids, W, bias, out);
    }
}

// Round 8
// 265.872 us; speedup vs baseline: 1.1487x; 1.1487x over previous
//
#include <hip/hip_runtime.h>
#include <hip/hip_bf16.h>

#define TSEQ 2048
#define TBZ  32
#define TDIM 1024
#define NLS  8

typedef __attribute__((ext_vector_type(8))) short bf16x8;
typedef __attribute__((ext_vector_type(4))) float f32x4;

__device__ inline unsigned int pk2(float lo, float hi) {
    __hip_bfloat162 h = __float22bfloat162_rn(make_float2(lo, hi)); // v_cvt_pk_bf16_f32
    return *reinterpret_cast<const unsigned int*>(&h);
}

__device__ inline void gload_lds16(const void* g, void* l) {
    __builtin_amdgcn_global_load_lds(
        (const __attribute__((address_space(1))) unsigned int*)g,
        (__attribute__((address_space(3))) unsigned int*)l,
        16, 0, 0);
}

// ---------- pass 1a: x -> xb [b][s][d] bf16 (active b) / out passthrough ----
// Block-uniform b (no divergence): grid = 32 b x 32 s-chunks of 64 rows.
__global__ __launch_bounds__(256) void conv_x(
    const float* __restrict__ x, const int* __restrict__ lang_ids,
    unsigned short* __restrict__ xb, float* __restrict__ out)
{
    const int b   = blockIdx.x >> 5;
    const int s0c = (blockIdx.x & 31) * 64;
    const int gid = 8 - lang_ids[b];
    const bool active = (gid >= 1) && (gid <= 8);

    for (int i = threadIdx.x; i < 64 * 128; i += 256) {
        const int ls = i >> 7;
        const int d8 = i & 127;
        const int s  = s0c + ls;
        const float* src = x + ((long)s * TBZ + b) * TDIM + d8 * 8;
        f32x4 v0 = *(const f32x4*)(src);
        f32x4 v1 = *(const f32x4*)(src + 4);
        if (active) {
            uint4 o;
            o.x = pk2(v0.x, v0.y); o.y = pk2(v0.z, v0.w);
            o.z = pk2(v1.x, v1.y); o.w = pk2(v1.z, v1.w);
            *(uint4*)(xb + ((long)b * TSEQ + s) * TDIM + d8 * 8) = o;
        } else {
            float* dst = out + ((long)s * TBZ + b) * TDIM + d8 * 8;
            *(f32x4*)(dst)     = v0;
            *(f32x4*)(dst + 4) = v1;
        }
    }
}

// ---------- pass 1b: W f32 -> bf16 ----------
__global__ __launch_bounds__(256) void conv_w(const float* __restrict__ W,
                                              unsigned short* __restrict__ wb) {
    const int total = NLS * TDIM * TDIM / 8;
    const int stride = gridDim.x * 256;
    for (int i = blockIdx.x * 256 + threadIdx.x; i < total; i += stride) {
        const float* src = W + (long)i * 8;
        f32x4 v0 = *(const f32x4*)(src);
        f32x4 v1 = *(const f32x4*)(src + 4);
        uint4 o;
        o.x = pk2(v0.x, v0.y); o.y = pk2(v0.z, v0.w);
        o.z = pk2(v1.x, v1.y); o.w = pk2(v1.z, v1.w);
        *(uint4*)(wb + (long)i * 8) = o;
    }
}

// ---------- pass 2: persistent 256x256 8-phase bf16 GEMM, 4 m-tiles/block ----
// Schedule/swizzle/reads/MFMA byte-identical to round 6 (verified). Strips of
// 4 m-tiles -> grid 256 (<=1 GEMM block per CU, single prologue). The KAo
// wrap generalizes: kv>>10 counts m-tiles ahead (+256 rows each). End-of-loop
// garbage prefetches only overwrite already-read LDS regions; b=31 row
// overflow reads land in wb (valid d_ws, never consumed).

#define BAR __builtin_amdgcn_s_barrier()
#define LGKM asm volatile("s_waitcnt lgkmcnt(0)" ::: "memory")
#define VMC(n) asm volatile("s_waitcnt vmcnt(" #n ")" ::: "memory")
#define KAo(kv) (((kv) & 1023) + (((kv) >> 10) << 18))
#define KBo(kv) ((kv) & 1023)

__global__ __launch_bounds__(512, 2) void mapper_gemm8p(
    const unsigned short* __restrict__ xb,      // [b][s][d] bf16
    const int* __restrict__ lang_ids,
    const unsigned short* __restrict__ wb,      // [e][out][in] bf16
    const float* __restrict__ bias,
    float* __restrict__ out)
{
    // XCD-chunked bijective swizzle: 256 = 8 * 32; nt fastest so the 4
    // blocks sharing an A strip-panel are consecutive on one XCD.
    const int p  = blockIdx.x;
    const int l  = (p & 7) * 32 + (p >> 3);
    const int b  = l >> 3;
    const int strip = (l >> 2) & 1;             // 4 m-tiles per strip
    const int nt = l & 3;
    const int s0 = strip * 1024;
    const int e0 = nt * 256;
    const int tid = threadIdx.x;

    const int gid = 8 - lang_ids[b];
    if (!(gid >= 1 && gid <= 8)) return;        // conv_x wrote passthrough
    const int eb = gid - 1;

    __shared__ uint4 ldsbuf[131072 / 16];
    char* ldsc = (char*)ldsbuf;

    const int lane = tid & 63;
    const int wave = tid >> 6;
    const int wr   = wave >> 2;
    const int wc   = wave & 3;
    const int fr   = lane & 15;
    const int fq   = lane >> 4;
    const int fr7  = fr & 7;

    const unsigned short* __restrict__ Aab = xb + (long)b  * TSEQ * TDIM + (long)s0 * TDIM;
    const unsigned short* __restrict__ Bbb = wb + (long)eb * TDIM * TDIM + (long)e0 * TDIM;

    const int L    = lane;
    const int lch8 = ((L & 7) ^ (L >> 3)) * 8;   // pre-inverse-swizzled global chunk
    const int ldA0 = wave * 2048 + L * 16;
    const unsigned short* aG[2][2];
    const unsigned short* bG[2][2];
    #pragma unroll
    for (int j = 0; j < 2; ++j) {
        const int rr = wave * 16 + j * 8 + (L >> 3);
        #pragma unroll
        for (int mh = 0; mh < 2; ++mh)
            aG[j][mh] = Aab + ((rr >> 6) * 128 + mh * 64 + (rr & 63)) * TDIM + lch8;
        #pragma unroll
        for (int nh = 0; nh < 2; ++nh)
            bG[j][nh] = Bbb + ((rr >> 5) * 64 + nh * 32 + (rr & 31)) * TDIM + lch8;
    }

#define STAGE_A(slot, mh, kofs) do { \
    gload_lds16(aG[0][mh] + (kofs), ldsc + (slot)*32768 + (mh)*16384 + ldA0); \
    gload_lds16(aG[1][mh] + (kofs), ldsc + (slot)*32768 + (mh)*16384 + ldA0 + 1024); \
} while (0)
#define STAGE_B(slot, nh, kofs) do { \
    gload_lds16(bG[0][nh] + (kofs), ldsc + 65536 + (slot)*32768 + (nh)*16384 + ldA0); \
    gload_lds16(bG[1][nh] + (kofs), ldsc + 65536 + (slot)*32768 + (nh)*16384 + ldA0 + 1024); \
} while (0)
#define RD_A(slot, mh) do { \
    _Pragma("unroll") for (int ml = 0; ml < 4; ++ml) { \
        const int rr = wr * 64 + ml * 16 + fr; \
        _Pragma("unroll") for (int kk = 0; kk < 2; ++kk) \
            af[ml][kk] = *(const bf16x8*)(ldsc + (slot)*32768 + (mh)*16384 + rr*128 + (((kk*4+fq) ^ fr7) << 4)); \
    } } while (0)
#define RD_B(slot, nh, br) do { \
    _Pragma("unroll") for (int nl = 0; nl < 2; ++nl) { \
        const int rr = wc * 32 + nl * 16 + fr; \
        _Pragma("unroll") for (int kk = 0; kk < 2; ++kk) \
            br[nl][kk] = *(const bf16x8*)(ldsc + 65536 + (slot)*32768 + (nh)*16384 + rr*128 + (((kk*4+fq) ^ fr7) << 4)); \
    } } while (0)
// Swapped operands (C^T): col=lane&15 -> s_local, row=(lane>>4)*4+j -> e_local.
#define MM(mh, nh, br) do { \
    __builtin_amdgcn_s_setprio(1); \
    _Pragma("unroll") for (int ml = 0; ml < 4; ++ml) \
    _Pragma("unroll") for (int nl = 0; nl < 2; ++nl) \
    _Pragma("unroll") for (int kk = 0; kk < 2; ++kk) \
        acc[(mh)*4+ml][(nh)*2+nl] = __builtin_amdgcn_mfma_f32_16x16x32_bf16( \
            br[nl][kk], af[ml][kk], acc[(mh)*4+ml][(nh)*2+nl], 0, 0, 0); \
    __builtin_amdgcn_s_setprio(0); \
} while (0)

    f32x4 acc[8][4];
    #pragma unroll
    for (int m = 0; m < 8; ++m)
        #pragma unroll
        for (int n = 0; n < 4; ++n)
            acc[m][n] = (f32x4){0.f, 0.f, 0.f, 0.f};

    bf16x8 af[4][2], bf0[2][2], bf1[2][2];

    // prologue: tile0 all 4 halves + tile1 {Amh0,Bnh0,Bnh1}
    STAGE_A(0, 0, 0);  STAGE_B(0, 0, 0);  STAGE_B(0, 1, 0);  STAGE_A(0, 1, 0);
    STAGE_A(1, 0, 64); STAGE_B(1, 0, 64); STAGE_B(1, 1, 64);
    VMC(6); BAR;

    const int cs  = lane & 15;          // s_local
    const int eqb = (lane >> 4) << 2;   // e_local base (4 consecutive)

    for (int mtl = 0; mtl < 4; ++mtl) {
        for (int it = 0; it < 8; ++it) {
            const int kva = mtl * 1024 + it * 128;
            const int kb = kva + 64;
            const int kn = kva + 128;   // wraps into next m-tile after it=7
            const int km = kva + 192;
            // P1
            RD_A(0, 0); RD_B(0, 0, bf0); STAGE_A(1, 1, KAo(kb));
            BAR; LGKM; MM(0, 0, bf0); BAR;
            // P2
            RD_B(0, 1, bf1); STAGE_A(0, 0, KAo(kn));
            BAR; LGKM; MM(0, 1, bf1); BAR;
            // P3
            RD_A(0, 1); STAGE_B(0, 0, KBo(kn));
            BAR; LGKM; MM(1, 0, bf0); BAR;
            // P4
            STAGE_B(0, 1, KBo(kn));
            BAR; MM(1, 1, bf1); VMC(6); BAR;
            // P5
            RD_A(1, 0); RD_B(1, 0, bf0); STAGE_A(0, 1, KAo(kn));
            BAR; LGKM; MM(0, 0, bf0); BAR;
            // P6
            RD_B(1, 1, bf1); STAGE_A(1, 0, KAo(km));
            BAR; LGKM; MM(0, 1, bf1); BAR;
            // P7
            RD_A(1, 1); STAGE_B(1, 0, KBo(km));
            BAR; LGKM; MM(1, 0, bf0); BAR;
            // P8
            STAGE_B(1, 1, KBo(km));
            BAR; MM(1, 1, bf1); VMC(6); BAR;
        }

        // epilogue: 32 dwordx4 stores; drain overlaps the bridge prefetch
        const int sb = s0 + mtl * 256 + wr * 128;
        #pragma unroll
        for (int n = 0; n < 4; ++n) {
            const int e = e0 + wc * 64 + n * 16 + eqb;
            const f32x4 bv4 = *(const f32x4*)&bias[eb * TDIM + e];
            #pragma unroll
            for (int m = 0; m < 8; ++m) {
                const int s = sb + m * 16 + cs;
                *(f32x4*)&out[(long)s * (TBZ * TDIM) + b * TDIM + e] = acc[m][n] + bv4;
            }
        }
        #pragma unroll
        for (int m = 0; m < 8; ++m)
            #pragma unroll
            for (int n = 0; n < 4; ++n)
                acc[m][n] = (f32x4){0.f, 0.f, 0.f, 0.f};
    }
#undef STAGE_A
#undef STAGE_B
#undef RD_A
#undef RD_B
#undef MM
}

// ---------- fallback: round-1 fused kernel ----------
__device__ inline unsigned short f2bf(float f) {
    union { float f; unsigned int u; } v; v.f = f;
    unsigned int r = v.u + 0x7fffu + ((v.u >> 16) & 1u);
    return (unsigned short)(r >> 16);
}
constexpr int FLDS = 40;

__global__ __launch_bounds__(256) void mapper_fused(
    const float* __restrict__ x, const int* __restrict__ lang_ids,
    const float* __restrict__ W, const float* __restrict__ bias,
    float* __restrict__ out)
{
    const int bid = blockIdx.x;
    const int b   = bid >> 7;
    const int t   = bid & 127;
    const int mt  = t >> 3;
    const int nt  = t & 7;
    const int s0  = mt * 128;
    const int e0  = nt * 128;
    const int tid = threadIdx.x;

    const int gid = 8 - lang_ids[b];
    const bool active = (gid >= 1) && (gid <= 8);
    int eb = gid - 1; eb = eb < 0 ? 0 : (eb > 7 ? 7 : eb);

    if (!active) {
        const f32x4* xs = (const f32x4*)x;
        f32x4*       os = (f32x4*)out;
        const int rs4 = TBZ * TDIM / 4;
        for (int i = tid; i < 128 * 128 / 4; i += 256) {
            int r = i >> 5, c = i & 31;
            long idx = (long)(s0 + r) * rs4 + b * (TDIM / 4) + (e0 >> 2) + c;
            os[idx] = xs[idx];
        }
        return;
    }

    __shared__ unsigned short As[128 * FLDS];
    __shared__ unsigned short Bs[128 * FLDS];
    const float* __restrict__ Wb = W + (long)eb * TDIM * TDIM;

    const int lane = tid & 63;
    const int wave = tid >> 6;
    const int wrr  = wave >> 1;
    const int wcc  = wave & 1;

    f32x4 acc[4][4];
    #pragma unroll
    for (int m = 0; m < 4; ++m)
        #pragma unroll
        for (int n = 0; n < 4; ++n)
            acc[m][n] = (f32x4){0.f, 0.f, 0.f, 0.f};

    const int rg = tid >> 3;
    const int cg = tid & 7;
    const int fr = lane & 15;
    const int fo = (lane >> 4) * 8;

    for (int k0 = 0; k0 < TDIM; k0 += 32) {
        __syncthreads();
        #pragma unroll
        for (int pp = 0; pp < 4; ++pp) {
            const int r = rg + pp * 32;
            f32x4 av = *(const f32x4*)(x  + (long)(s0 + r) * (TBZ * TDIM) + b * TDIM + k0 + cg * 4);
            f32x4 bv = *(const f32x4*)(Wb + (long)(e0 + r) * TDIM + k0 + cg * 4);
            unsigned int alo = (unsigned)f2bf(av.x) | ((unsigned)f2bf(av.y) << 16);
            unsigned int ahi = (unsigned)f2bf(av.z) | ((unsigned)f2bf(av.w) << 16);
            unsigned int blo = (unsigned)f2bf(bv.x) | ((unsigned)f2bf(bv.y) << 16);
            unsigned int bhi = (unsigned)f2bf(bv.z) | ((unsigned)f2bf(bv.w) << 16);
            *(uint2*)&As[r * FLDS + cg * 4] = make_uint2(alo, ahi);
            *(uint2*)&Bs[r * FLDS + cg * 4] = make_uint2(blo, bhi);
        }
        __syncthreads();

        bf16x8 af2[4], bfm[4];
        #pragma unroll
        for (int m = 0; m < 4; ++m)
            af2[m] = *(const bf16x8*)&As[(wrr * 64 + m * 16 + fr) * FLDS + fo];
        #pragma unroll
        for (int n = 0; n < 4; ++n)
            bfm[n] = *(const bf16x8*)&Bs[(wcc * 64 + n * 16 + fr) * FLDS + fo];
        #pragma unroll
        for (int m = 0; m < 4; ++m)
            #pragma unroll
            for (int n = 0; n < 4; ++n)
                acc[m][n] = __builtin_amdgcn_mfma_f32_16x16x32_bf16(af2[m], bfm[n], acc[m][n], 0, 0, 0);
    }

    const int cr = lane >> 4;
    const int cc2 = lane & 15;
    #pragma unroll
    for (int n = 0; n < 4; ++n) {
        const int e  = e0 + wcc * 64 + n * 16 + cc2;
        const float bv = bias[eb * TDIM + e];
        #pragma unroll
        for (int m = 0; m < 4; ++m) {
            #pragma unroll
            for (int j = 0; j < 4; ++j) {
                const int s = s0 + wrr * 64 + m * 16 + cr * 4 + j;
                out[(long)s * (TBZ * TDIM) + b * TDIM + e] = acc[m][n][j] + bv;
            }
        }
    }
}

extern "C" void kernel_launch(void* const* d_in, const int* in_sizes, int n_in,
                              void* d_out, int out_size, void* d_ws, size_t ws_size,
                              hipStream_t stream) {
    const float* x        = (const float*)d_in[0];
    const int*   lang_ids = (const int*)d_in[1];
    const float* W        = (const float*)d_in[2];
    const float* bias     = (const float*)d_in[3];
    float*       out      = (float*)d_out;

    const size_t xbytes = (size_t)TSEQ * TBZ * TDIM * 2;   // 128 MiB
    const size_t wbytes = (size_t)NLS * TDIM * TDIM * 2;   // 16 MiB

    if (ws_size >= xbytes + wbytes) {
        unsigned short* xbp = (unsigned short*)d_ws;
        unsigned short* wbp = (unsigned short*)((char*)d_ws + xbytes);
        conv_x<<<1024, 256, 0, stream>>>(x, lang_ids, xbp, out);
        conv_w<<<2048, 256, 0, stream>>>(W, wbp);
        mapper_gemm8p<<<256, 512, 0, stream>>>(xbp, lang_ids, wbp, bias, out);
    } else {
        mapper_fused<<<TBZ * 16 * 8, 256, 0, stream>>>(x, lang_ids, W, bias, out);
    }
}

// Round 9
// 261.470 us; speedup vs baseline: 1.1680x; 1.0168x over previous
//
#include <hip/hip_runtime.h>
#include <hip/hip_bf16.h>

#define TSEQ 2048
#define TBZ  32
#define TDIM 1024
#define NLS  8

typedef __attribute__((ext_vector_type(8))) short bf16x8;
typedef __attribute__((ext_vector_type(4))) float f32x4;

__device__ inline unsigned int pk2(float lo, float hi) {
    __hip_bfloat162 h = __float22bfloat162_rn(make_float2(lo, hi)); // v_cvt_pk_bf16_f32
    return *reinterpret_cast<const unsigned int*>(&h);
}

__device__ inline void gload_lds16(const void* g, void* l) {
    __builtin_amdgcn_global_load_lds(
        (const __attribute__((address_space(1))) unsigned int*)g,
        (__attribute__((address_space(3))) unsigned int*)l,
        16, 0, 0);
}

// ---------- pass 1: merged conversion, one dispatch, block-uniform roles ----
// Blocks [0,256):    W f32 -> bf16 (runs concurrently with x-part)
// Blocks [256,2304): x -> xb [b][s][d] bf16 (active b) / out passthrough
__global__ __launch_bounds__(256) void conv_all(
    const float* __restrict__ x, const int* __restrict__ lang_ids,
    const float* __restrict__ W,
    unsigned short* __restrict__ xb, unsigned short* __restrict__ wb,
    float* __restrict__ out)
{
    const int bid = blockIdx.x;
    if (bid < 256) {                               // W part: 1M chunks of 8
        const int total = NLS * TDIM * TDIM / 8;
        for (int i = bid * 256 + threadIdx.x; i < total; i += 256 * 256) {
            const float* src = W + (long)i * 8;
            f32x4 v0 = *(const f32x4*)(src);
            f32x4 v1 = *(const f32x4*)(src + 4);
            uint4 o;
            o.x = pk2(v0.x, v0.y); o.y = pk2(v0.z, v0.w);
            o.z = pk2(v1.x, v1.y); o.w = pk2(v1.z, v1.w);
            *(uint4*)(wb + (long)i * 8) = o;
        }
        return;
    }
    // x part: 2048 blocks = 32 b x 64 s-chunks of 32 rows, block-uniform b
    const int xb_id = bid - 256;
    const int b     = xb_id >> 6;
    const int s0c   = (xb_id & 63) * 32;
    const int gid   = 8 - lang_ids[b];
    const bool active = (gid >= 1) && (gid <= 8);

    for (int i = threadIdx.x; i < 32 * 128; i += 256) {
        const int ls = i >> 7;
        const int d8 = i & 127;
        const int s  = s0c + ls;
        const float* src = x + ((long)s * TBZ + b) * TDIM + d8 * 8;
        f32x4 v0 = *(const f32x4*)(src);
        f32x4 v1 = *(const f32x4*)(src + 4);
        if (active) {
            uint4 o;
            o.x = pk2(v0.x, v0.y); o.y = pk2(v0.z, v0.w);
            o.z = pk2(v1.x, v1.y); o.w = pk2(v1.z, v1.w);
            *(uint4*)(xb + ((long)b * TSEQ + s) * TDIM + d8 * 8) = o;
        } else {
            float* dst = out + ((long)s * TBZ + b) * TDIM + d8 * 8;
            *(f32x4*)(dst)     = v0;
            *(f32x4*)(dst + 4) = v1;
        }
    }
}

// ---------- pass 2: persistent 256x256 8-phase bf16 GEMM, 4 m-tiles/block ----
// Schedule/swizzle/stages/VMC identical to rounds 6/8 (verified twice).
// CHANGE vs r8: the blanket `s_waitcnt lgkmcnt(0)` after each pre-MFMA
// barrier is replaced by sched_barrier(0) (compile-time pin only). The
// compiler then emits fine-grained lgkmcnt(N) per MFMA operand dependency
// (m97 behavior), overlapping the ds_read completion tail under MFMA issue
// instead of serializing all-12-reads -> all-16-MFMAs every phase.
// sched_barrier(0) after EVERY s_barrier prevents ds_read/MFMA hoisting
// across barriers (rule #18/#21 hazards) while leaving in-phase scheduling
// free (m141's mistake was pinning around every op).

#define BAR __builtin_amdgcn_s_barrier()
#define SB0 __builtin_amdgcn_sched_barrier(0)
#define VMC(n) asm volatile("s_waitcnt vmcnt(" #n ")" ::: "memory")
#define KAo(kv) (((kv) & 1023) + (((kv) >> 10) << 18))
#define KBo(kv) ((kv) & 1023)

__global__ __launch_bounds__(512, 2) void mapper_gemm8p(
    const unsigned short* __restrict__ xb,      // [b][s][d] bf16
    const int* __restrict__ lang_ids,
    const unsigned short* __restrict__ wb,      // [e][out][in] bf16
    const float* __restrict__ bias,
    float* __restrict__ out)
{
    // XCD-chunked bijective swizzle: 256 = 8 * 32; nt fastest so the 4
    // blocks sharing an A strip-panel are consecutive on one XCD.
    const int p  = blockIdx.x;
    const int l  = (p & 7) * 32 + (p >> 3);
    const int b  = l >> 3;
    const int strip = (l >> 2) & 1;             // 4 m-tiles per strip
    const int nt = l & 3;
    const int s0 = strip * 1024;
    const int e0 = nt * 256;
    const int tid = threadIdx.x;

    const int gid = 8 - lang_ids[b];
    if (!(gid >= 1 && gid <= 8)) return;        // conv_all wrote passthrough
    const int eb = gid - 1;

    __shared__ uint4 ldsbuf[131072 / 16];
    char* ldsc = (char*)ldsbuf;

    const int lane = tid & 63;
    const int wave = tid >> 6;
    const int wr   = wave >> 2;
    const int wc   = wave & 3;
    const int fr   = lane & 15;
    const int fq   = lane >> 4;
    const int fr7  = fr & 7;

    const unsigned short* __restrict__ Aab = xb + (long)b  * TSEQ * TDIM + (long)s0 * TDIM;
    const unsigned short* __restrict__ Bbb = wb + (long)eb * TDIM * TDIM + (long)e0 * TDIM;

    const int L    = lane;
    const int lch8 = ((L & 7) ^ (L >> 3)) * 8;   // pre-inverse-swizzled global chunk
    const int ldA0 = wave * 2048 + L * 16;
    const unsigned short* aG[2][2];
    const unsigned short* bG[2][2];
    #pragma unroll
    for (int j = 0; j < 2; ++j) {
        const int rr = wave * 16 + j * 8 + (L >> 3);
        #pragma unroll
        for (int mh = 0; mh < 2; ++mh)
            aG[j][mh] = Aab + ((rr >> 6) * 128 + mh * 64 + (rr & 63)) * TDIM + lch8;
        #pragma unroll
        for (int nh = 0; nh < 2; ++nh)
            bG[j][nh] = Bbb + ((rr >> 5) * 64 + nh * 32 + (rr & 31)) * TDIM + lch8;
    }

#define STAGE_A(slot, mh, kofs) do { \
    gload_lds16(aG[0][mh] + (kofs), ldsc + (slot)*32768 + (mh)*16384 + ldA0); \
    gload_lds16(aG[1][mh] + (kofs), ldsc + (slot)*32768 + (mh)*16384 + ldA0 + 1024); \
} while (0)
#define STAGE_B(slot, nh, kofs) do { \
    gload_lds16(bG[0][nh] + (kofs), ldsc + 65536 + (slot)*32768 + (nh)*16384 + ldA0); \
    gload_lds16(bG[1][nh] + (kofs), ldsc + 65536 + (slot)*32768 + (nh)*16384 + ldA0 + 1024); \
} while (0)
#define RD_A(slot, mh) do { \
    _Pragma("unroll") for (int ml = 0; ml < 4; ++ml) { \
        const int rr = wr * 64 + ml * 16 + fr; \
        _Pragma("unroll") for (int kk = 0; kk < 2; ++kk) \
            af[ml][kk] = *(const bf16x8*)(ldsc + (slot)*32768 + (mh)*16384 + rr*128 + (((kk*4+fq) ^ fr7) << 4)); \
    } } while (0)
#define RD_B(slot, nh, br) do { \
    _Pragma("unroll") for (int nl = 0; nl < 2; ++nl) { \
        const int rr = wc * 32 + nl * 16 + fr; \
        _Pragma("unroll") for (int kk = 0; kk < 2; ++kk) \
            br[nl][kk] = *(const bf16x8*)(ldsc + 65536 + (slot)*32768 + (nh)*16384 + rr*128 + (((kk*4+fq) ^ fr7) << 4)); \
    } } while (0)
// Swapped operands (C^T): col=lane&15 -> s_local, row=(lane>>4)*4+j -> e_local.
#define MM(mh, nh, br) do { \
    __builtin_amdgcn_s_setprio(1); \
    _Pragma("unroll") for (int ml = 0; ml < 4; ++ml) \
    _Pragma("unroll") for (int nl = 0; nl < 2; ++nl) \
    _Pragma("unroll") for (int kk = 0; kk < 2; ++kk) \
        acc[(mh)*4+ml][(nh)*2+nl] = __builtin_amdgcn_mfma_f32_16x16x32_bf16( \
            br[nl][kk], af[ml][kk], acc[(mh)*4+ml][(nh)*2+nl], 0, 0, 0); \
    __builtin_amdgcn_s_setprio(0); \
} while (0)

    f32x4 acc[8][4];
    #pragma unroll
    for (int m = 0; m < 8; ++m)
        #pragma unroll
        for (int n = 0; n < 4; ++n)
            acc[m][n] = (f32x4){0.f, 0.f, 0.f, 0.f};

    bf16x8 af[4][2], bf0[2][2], bf1[2][2];

    // prologue: tile0 all 4 halves + tile1 {Amh0,Bnh0,Bnh1}
    STAGE_A(0, 0, 0);  STAGE_B(0, 0, 0);  STAGE_B(0, 1, 0);  STAGE_A(0, 1, 0);
    STAGE_A(1, 0, 64); STAGE_B(1, 0, 64); STAGE_B(1, 1, 64);
    VMC(6); BAR; SB0;

    const int cs  = lane & 15;          // s_local
    const int eqb = (lane >> 4) << 2;   // e_local base (4 consecutive)

    for (int mtl = 0; mtl < 4; ++mtl) {
        for (int it = 0; it < 8; ++it) {
            const int kva = mtl * 1024 + it * 128;
            const int kb = kva + 64;
            const int kn = kva + 128;   // wraps into next m-tile after it=7
            const int km = kva + 192;
            // P1
            RD_A(0, 0); RD_B(0, 0, bf0); STAGE_A(1, 1, KAo(kb));
            BAR; SB0; MM(0, 0, bf0); BAR; SB0;
            // P2
            RD_B(0, 1, bf1); STAGE_A(0, 0, KAo(kn));
            BAR; SB0; MM(0, 1, bf1); BAR; SB0;
            // P3
            RD_A(0, 1); STAGE_B(0, 0, KBo(kn));
            BAR; SB0; MM(1, 0, bf0); BAR; SB0;
            // P4
            STAGE_B(0, 1, KBo(kn));
            BAR; SB0; MM(1, 1, bf1); VMC(6); BAR; SB0;
            // P5
            RD_A(1, 0); RD_B(1, 0, bf0); STAGE_A(0, 1, KAo(kn));
            BAR; SB0; MM(0, 0, bf0); BAR; SB0;
            // P6
            RD_B(1, 1, bf1); STAGE_A(1, 0, KAo(km));
            BAR; SB0; MM(0, 1, bf1); BAR; SB0;
            // P7
            RD_A(1, 1); STAGE_B(1, 0, KBo(km));
            BAR; SB0; MM(1, 0, bf0); BAR; SB0;
            // P8
            STAGE_B(1, 1, KBo(km));
            BAR; SB0; MM(1, 1, bf1); VMC(6); BAR; SB0;
        }

        // epilogue: 32 dwordx4 stores; drain overlaps the bridge prefetch
        const int sb = s0 + mtl * 256 + wr * 128;
        #pragma unroll
        for (int n = 0; n < 4; ++n) {
            const int e = e0 + wc * 64 + n * 16 + eqb;
            const f32x4 bv4 = *(const f32x4*)&bias[eb * TDIM + e];
            #pragma unroll
            for (int m = 0; m < 8; ++m) {
                const int s = sb + m * 16 + cs;
                *(f32x4*)&out[(long)s * (TBZ * TDIM) + b * TDIM + e] = acc[m][n] + bv4;
            }
        }
        #pragma unroll
        for (int m = 0; m < 8; ++m)
            #pragma unroll
            for (int n = 0; n < 4; ++n)
                acc[m][n] = (f32x4){0.f, 0.f, 0.f, 0.f};
    }
#undef STAGE_A
#undef STAGE_B
#undef RD_A
#undef RD_B
#undef MM
}

// ---------- fallback: round-1 fused kernel ----------
__device__ inline unsigned short f2bf(float f) {
    union { float f; unsigned int u; } v; v.f = f;
    unsigned int r = v.u + 0x7fffu + ((v.u >> 16) & 1u);
    return (unsigned short)(r >> 16);
}
constexpr int FLDS = 40;

__global__ __launch_bounds__(256) void mapper_fused(
    const float* __restrict__ x, const int* __restrict__ lang_ids,
    const float* __restrict__ W, const float* __restrict__ bias,
    float* __restrict__ out)
{
    const int bid = blockIdx.x;
    const int b   = bid >> 7;
    const int t   = bid & 127;
    const int mt  = t >> 3;
    const int nt  = t & 7;
    const int s0  = mt * 128;
    const int e0  = nt * 128;
    const int tid = threadIdx.x;

    const int gid = 8 - lang_ids[b];
    const bool active = (gid >= 1) && (gid <= 8);
    int eb = gid - 1; eb = eb < 0 ? 0 : (eb > 7 ? 7 : eb);

    if (!active) {
        const f32x4* xs = (const f32x4*)x;
        f32x4*       os = (f32x4*)out;
        const int rs4 = TBZ * TDIM / 4;
        for (int i = tid; i < 128 * 128 / 4; i += 256) {
            int r = i >> 5, c = i & 31;
            long idx = (long)(s0 + r) * rs4 + b * (TDIM / 4) + (e0 >> 2) + c;
            os[idx] = xs[idx];
        }
        return;
    }

    __shared__ unsigned short As[128 * FLDS];
    __shared__ unsigned short Bs[128 * FLDS];
    const float* __restrict__ Wb = W + (long)eb * TDIM * TDIM;

    const int lane = tid & 63;
    const int wave = tid >> 6;
    const int wrr  = wave >> 1;
    const int wcc  = wave & 1;

    f32x4 acc[4][4];
    #pragma unroll
    for (int m = 0; m < 4; ++m)
        #pragma unroll
        for (int n = 0; n < 4; ++n)
            acc[m][n] = (f32x4){0.f, 0.f, 0.f, 0.f};

    const int rg = tid >> 3;
    const int cg = tid & 7;
    const int fr = lane & 15;
    const int fo = (lane >> 4) * 8;

    for (int k0 = 0; k0 < TDIM; k0 += 32) {
        __syncthreads();
        #pragma unroll
        for (int pp = 0; pp < 4; ++pp) {
            const int r = rg + pp * 32;
            f32x4 av = *(const f32x4*)(x  + (long)(s0 + r) * (TBZ * TDIM) + b * TDIM + k0 + cg * 4);
            f32x4 bv = *(const f32x4*)(Wb + (long)(e0 + r) * TDIM + k0 + cg * 4);
            unsigned int alo = (unsigned)f2bf(av.x) | ((unsigned)f2bf(av.y) << 16);
            unsigned int ahi = (unsigned)f2bf(av.z) | ((unsigned)f2bf(av.w) << 16);
            unsigned int blo = (unsigned)f2bf(bv.x) | ((unsigned)f2bf(bv.y) << 16);
            unsigned int bhi = (unsigned)f2bf(bv.z) | ((unsigned)f2bf(bv.w) << 16);
            *(uint2*)&As[r * FLDS + cg * 4] = make_uint2(alo, ahi);
            *(uint2*)&Bs[r * FLDS + cg * 4] = make_uint2(blo, bhi);
        }
        __syncthreads();

        bf16x8 af2[4], bfm[4];
        #pragma unroll
        for (int m = 0; m < 4; ++m)
            af2[m] = *(const bf16x8*)&As[(wrr * 64 + m * 16 + fr) * FLDS + fo];
        #pragma unroll
        for (int n = 0; n < 4; ++n)
            bfm[n] = *(const bf16x8*)&Bs[(wcc * 64 + n * 16 + fr) * FLDS + fo];
        #pragma unroll
        for (int m = 0; m < 4; ++m)
            #pragma unroll
            for (int n = 0; n < 4; ++n)
                acc[m][n] = __builtin_amdgcn_mfma_f32_16x16x32_bf16(af2[m], bfm[n], acc[m][n], 0, 0, 0);
    }

    const int cr = lane >> 4;
    const int cc2 = lane & 15;
    #pragma unroll
    for (int n = 0; n < 4; ++n) {
        const int e  = e0 + wcc * 64 + n * 16 + cc2;
        const float bv = bias[eb * TDIM + e];
        #pragma unroll
        for (int m = 0; m < 4; ++m) {
            #pragma unroll
            for (int j = 0; j < 4; ++j) {
                const int s = s0 + wrr * 64 + m * 16 + cr * 4 + j;
                out[(long)s * (TBZ * TDIM) + b * TDIM + e] = acc[m][n][j] + bv;
            }
        }
    }
}

extern "C" void kernel_launch(void* const* d_in, const int* in_sizes, int n_in,
                              void* d_out, int out_size, void* d_ws, size_t ws_size,
                              hipStream_t stream) {
    const float* x        = (const float*)d_in[0];
    const int*   lang_ids = (const int*)d_in[1];
    const float* W        = (const float*)d_in[2];
    const float* bias     = (const float*)d_in[3];
    float*       out      = (float*)d_out;

    const size_t xbytes = (size_t)TSEQ * TBZ * TDIM * 2;   // 128 MiB
    const size_t wbytes = (size_t)NLS * TDIM * TDIM * 2;   // 16 MiB

    if (ws_size >= xbytes + wbytes) {
        unsigned short* xbp = (unsigned short*)d_ws;
        unsigned short* wbp = (unsigned short*)((char*)d_ws + xbytes);
        conv_all<<<2304, 256, 0, stream>>>(x, lang_ids, W, xbp, wbp, out);
        mapper_gemm8p<<<256, 512, 0, stream>>>(xbp, lang_ids, wbp, bias, out);
    } else {
        mapper_fused<<<TBZ * 16 * 8, 256, 0, stream>>>(x, lang_ids, W, bias, out);
    }
}

// Round 10
// 259.557 us; speedup vs baseline: 1.1766x; 1.0074x over previous
//
#include <hip/hip_runtime.h>
#include <hip/hip_bf16.h>

#define TSEQ 2048
#define TBZ  32
#define TDIM 1024
#define NLS  8

typedef __attribute__((ext_vector_type(8))) short bf16x8;
typedef __attribute__((ext_vector_type(4))) float f32x4;

__device__ inline unsigned int pk2(float lo, float hi) {
    __hip_bfloat162 h = __float22bfloat162_rn(make_float2(lo, hi)); // v_cvt_pk_bf16_f32
    return *reinterpret_cast<const unsigned int*>(&h);
}

__device__ inline void gload_lds16(const void* g, void* l) {
    __builtin_amdgcn_global_load_lds(
        (const __attribute__((address_space(1))) unsigned int*)g,
        (__attribute__((address_space(3))) unsigned int*)l,
        16, 0, 0);
}

// ---------- pass 1: merged conversion, one dispatch, block-uniform roles ----
__global__ __launch_bounds__(256) void conv_all(
    const float* __restrict__ x, const int* __restrict__ lang_ids,
    const float* __restrict__ W,
    unsigned short* __restrict__ xb, unsigned short* __restrict__ wb,
    float* __restrict__ out)
{
    const int bid = blockIdx.x;
    if (bid < 256) {                               // W part: 1M chunks of 8
        const int total = NLS * TDIM * TDIM / 8;
        for (int i = bid * 256 + threadIdx.x; i < total; i += 256 * 256) {
            const float* src = W + (long)i * 8;
            f32x4 v0 = *(const f32x4*)(src);
            f32x4 v1 = *(const f32x4*)(src + 4);
            uint4 o;
            o.x = pk2(v0.x, v0.y); o.y = pk2(v0.z, v0.w);
            o.z = pk2(v1.x, v1.y); o.w = pk2(v1.z, v1.w);
            *(uint4*)(wb + (long)i * 8) = o;
        }
        return;
    }
    // x part: 2048 blocks = 32 b x 64 s-chunks of 32 rows, block-uniform b
    const int xb_id = bid - 256;
    const int b     = xb_id >> 6;
    const int s0c   = (xb_id & 63) * 32;
    const int gid   = 8 - lang_ids[b];
    const bool active = (gid >= 1) && (gid <= 8);

    for (int i = threadIdx.x; i < 32 * 128; i += 256) {
        const int ls = i >> 7;
        const int d8 = i & 127;
        const int s  = s0c + ls;
        const float* src = x + ((long)s * TBZ + b) * TDIM + d8 * 8;
        f32x4 v0 = *(const f32x4*)(src);
        f32x4 v1 = *(const f32x4*)(src + 4);
        if (active) {
            uint4 o;
            o.x = pk2(v0.x, v0.y); o.y = pk2(v0.z, v0.w);
            o.z = pk2(v1.x, v1.y); o.w = pk2(v1.z, v1.w);
            *(uint4*)(xb + ((long)b * TSEQ + s) * TDIM + d8 * 8) = o;
        } else {
            float* dst = out + ((long)s * TBZ + b) * TDIM + d8 * 8;
            *(f32x4*)(dst)     = v0;
            *(f32x4*)(dst + 4) = v1;
        }
    }
}

// ---------- pass 2: persistent 256x256 8-phase bf16 GEMM, 4 m-tiles/block ----
// Schedule/swizzle/stages/VMC identical to rounds 6/8/9 (verified 3x).
// CHANGE vs r9: `#pragma unroll 1` on the mtl and it loops. Previously both
// loops had constant trip counts -> the compiler fully unrolled 32 iterations
// x 8 phases (>10k instr, ~40+ KB) -> I-cache thrash: every iteration
// re-fetches the body from L2, a uniform stall invisible to SQ counters
// (MfmaUtil 30 / VALU 12 / conflicts 0 / HBM 40% with nothing busy). Rolled
// body ~350 instr fits I-cache; KAo/KBo become 3 uniform SALU ops.

#define BAR __builtin_amdgcn_s_barrier()
#define SB0 __builtin_amdgcn_sched_barrier(0)
#define VMC(n) asm volatile("s_waitcnt vmcnt(" #n ")" ::: "memory")
#define KAo(kv) (((kv) & 1023) + (((kv) >> 10) << 18))
#define KBo(kv) ((kv) & 1023)

__global__ __launch_bounds__(512, 2) void mapper_gemm8p(
    const unsigned short* __restrict__ xb,      // [b][s][d] bf16
    const int* __restrict__ lang_ids,
    const unsigned short* __restrict__ wb,      // [e][out][in] bf16
    const float* __restrict__ bias,
    float* __restrict__ out)
{
    // XCD-chunked bijective swizzle: 256 = 8 * 32; nt fastest so the 4
    // blocks sharing an A strip-panel are consecutive on one XCD.
    const int p  = blockIdx.x;
    const int l  = (p & 7) * 32 + (p >> 3);
    const int b  = l >> 3;
    const int strip = (l >> 2) & 1;             // 4 m-tiles per strip
    const int nt = l & 3;
    const int s0 = strip * 1024;
    const int e0 = nt * 256;
    const int tid = threadIdx.x;

    const int gid = 8 - lang_ids[b];
    if (!(gid >= 1 && gid <= 8)) return;        // conv_all wrote passthrough
    const int eb = gid - 1;

    __shared__ uint4 ldsbuf[131072 / 16];
    char* ldsc = (char*)ldsbuf;

    const int lane = tid & 63;
    const int wave = tid >> 6;
    const int wr   = wave >> 2;
    const int wc   = wave & 3;
    const int fr   = lane & 15;
    const int fq   = lane >> 4;
    const int fr7  = fr & 7;

    const unsigned short* __restrict__ Aab = xb + (long)b  * TSEQ * TDIM + (long)s0 * TDIM;
    const unsigned short* __restrict__ Bbb = wb + (long)eb * TDIM * TDIM + (long)e0 * TDIM;

    const int L    = lane;
    const int lch8 = ((L & 7) ^ (L >> 3)) * 8;   // pre-inverse-swizzled global chunk
    const int ldA0 = wave * 2048 + L * 16;
    const unsigned short* aG[2][2];
    const unsigned short* bG[2][2];
    #pragma unroll
    for (int j = 0; j < 2; ++j) {
        const int rr = wave * 16 + j * 8 + (L >> 3);
        #pragma unroll
        for (int mh = 0; mh < 2; ++mh)
            aG[j][mh] = Aab + ((rr >> 6) * 128 + mh * 64 + (rr & 63)) * TDIM + lch8;
        #pragma unroll
        for (int nh = 0; nh < 2; ++nh)
            bG[j][nh] = Bbb + ((rr >> 5) * 64 + nh * 32 + (rr & 31)) * TDIM + lch8;
    }

#define STAGE_A(slot, mh, kofs) do { \
    gload_lds16(aG[0][mh] + (kofs), ldsc + (slot)*32768 + (mh)*16384 + ldA0); \
    gload_lds16(aG[1][mh] + (kofs), ldsc + (slot)*32768 + (mh)*16384 + ldA0 + 1024); \
} while (0)
#define STAGE_B(slot, nh, kofs) do { \
    gload_lds16(bG[0][nh] + (kofs), ldsc + 65536 + (slot)*32768 + (nh)*16384 + ldA0); \
    gload_lds16(bG[1][nh] + (kofs), ldsc + 65536 + (slot)*32768 + (nh)*16384 + ldA0 + 1024); \
} while (0)
#define RD_A(slot, mh) do { \
    _Pragma("unroll") for (int ml = 0; ml < 4; ++ml) { \
        const int rr = wr * 64 + ml * 16 + fr; \
        _Pragma("unroll") for (int kk = 0; kk < 2; ++kk) \
            af[ml][kk] = *(const bf16x8*)(ldsc + (slot)*32768 + (mh)*16384 + rr*128 + (((kk*4+fq) ^ fr7) << 4)); \
    } } while (0)
#define RD_B(slot, nh, br) do { \
    _Pragma("unroll") for (int nl = 0; nl < 2; ++nl) { \
        const int rr = wc * 32 + nl * 16 + fr; \
        _Pragma("unroll") for (int kk = 0; kk < 2; ++kk) \
            br[nl][kk] = *(const bf16x8*)(ldsc + 65536 + (slot)*32768 + (nh)*16384 + rr*128 + (((kk*4+fq) ^ fr7) << 4)); \
    } } while (0)
// Swapped operands (C^T): col=lane&15 -> s_local, row=(lane>>4)*4+j -> e_local.
#define MM(mh, nh, br) do { \
    __builtin_amdgcn_s_setprio(1); \
    _Pragma("unroll") for (int ml = 0; ml < 4; ++ml) \
    _Pragma("unroll") for (int nl = 0; nl < 2; ++nl) \
    _Pragma("unroll") for (int kk = 0; kk < 2; ++kk) \
        acc[(mh)*4+ml][(nh)*2+nl] = __builtin_amdgcn_mfma_f32_16x16x32_bf16( \
            br[nl][kk], af[ml][kk], acc[(mh)*4+ml][(nh)*2+nl], 0, 0, 0); \
    __builtin_amdgcn_s_setprio(0); \
} while (0)

    f32x4 acc[8][4];
    #pragma unroll
    for (int m = 0; m < 8; ++m)
        #pragma unroll
        for (int n = 0; n < 4; ++n)
            acc[m][n] = (f32x4){0.f, 0.f, 0.f, 0.f};

    bf16x8 af[4][2], bf0[2][2], bf1[2][2];

    // prologue: tile0 all 4 halves + tile1 {Amh0,Bnh0,Bnh1}
    STAGE_A(0, 0, 0);  STAGE_B(0, 0, 0);  STAGE_B(0, 1, 0);  STAGE_A(0, 1, 0);
    STAGE_A(1, 0, 64); STAGE_B(1, 0, 64); STAGE_B(1, 1, 64);
    VMC(6); BAR; SB0;

    const int cs  = lane & 15;          // s_local
    const int eqb = (lane >> 4) << 2;   // e_local base (4 consecutive)

    #pragma unroll 1
    for (int mtl = 0; mtl < 4; ++mtl) {
        #pragma unroll 1
        for (int it = 0; it < 8; ++it) {
            const int kva = mtl * 1024 + it * 128;
            const int kb = kva + 64;
            const int kn = kva + 128;   // wraps into next m-tile after it=7
            const int km = kva + 192;
            // P1
            RD_A(0, 0); RD_B(0, 0, bf0); STAGE_A(1, 1, KAo(kb));
            BAR; SB0; MM(0, 0, bf0); BAR; SB0;
            // P2
            RD_B(0, 1, bf1); STAGE_A(0, 0, KAo(kn));
            BAR; SB0; MM(0, 1, bf1); BAR; SB0;
            // P3
            RD_A(0, 1); STAGE_B(0, 0, KBo(kn));
            BAR; SB0; MM(1, 0, bf0); BAR; SB0;
            // P4
            STAGE_B(0, 1, KBo(kn));
            BAR; SB0; MM(1, 1, bf1); VMC(6); BAR; SB0;
            // P5
            RD_A(1, 0); RD_B(1, 0, bf0); STAGE_A(0, 1, KAo(kn));
            BAR; SB0; MM(0, 0, bf0); BAR; SB0;
            // P6
            RD_B(1, 1, bf1); STAGE_A(1, 0, KAo(km));
            BAR; SB0; MM(0, 1, bf1); BAR; SB0;
            // P7
            RD_A(1, 1); STAGE_B(1, 0, KBo(km));
            BAR; SB0; MM(1, 0, bf0); BAR; SB0;
            // P8
            STAGE_B(1, 1, KBo(km));
            BAR; SB0; MM(1, 1, bf1); VMC(6); BAR; SB0;
        }

        // epilogue: 32 dwordx4 stores; drain overlaps the bridge prefetch
        const int sb = s0 + mtl * 256 + wr * 128;
        #pragma unroll
        for (int n = 0; n < 4; ++n) {
            const int e = e0 + wc * 64 + n * 16 + eqb;
            const f32x4 bv4 = *(const f32x4*)&bias[eb * TDIM + e];
            #pragma unroll
            for (int m = 0; m < 8; ++m) {
                const int s = sb + m * 16 + cs;
                *(f32x4*)&out[(long)s * (TBZ * TDIM) + b * TDIM + e] = acc[m][n] + bv4;
            }
        }
        #pragma unroll
        for (int m = 0; m < 8; ++m)
            #pragma unroll
            for (int n = 0; n < 4; ++n)
                acc[m][n] = (f32x4){0.f, 0.f, 0.f, 0.f};
    }
#undef STAGE_A
#undef STAGE_B
#undef RD_A
#undef RD_B
#undef MM
}

// ---------- fallback: round-1 fused kernel ----------
__device__ inline unsigned short f2bf(float f) {
    union { float f; unsigned int u; } v; v.f = f;
    unsigned int r = v.u + 0x7fffu + ((v.u >> 16) & 1u);
    return (unsigned short)(r >> 16);
}
constexpr int FLDS = 40;

__global__ __launch_bounds__(256) void mapper_fused(
    const float* __restrict__ x, const int* __restrict__ lang_ids,
    const float* __restrict__ W, const float* __restrict__ bias,
    float* __restrict__ out)
{
    const int bid = blockIdx.x;
    const int b   = bid >> 7;
    const int t   = bid & 127;
    const int mt  = t >> 3;
    const int nt  = t & 7;
    const int s0  = mt * 128;
    const int e0  = nt * 128;
    const int tid = threadIdx.x;

    const int gid = 8 - lang_ids[b];
    const bool active = (gid >= 1) && (gid <= 8);
    int eb = gid - 1; eb = eb < 0 ? 0 : (eb > 7 ? 7 : eb);

    if (!active) {
        const f32x4* xs = (const f32x4*)x;
        f32x4*       os = (f32x4*)out;
        const int rs4 = TBZ * TDIM / 4;
        for (int i = tid; i < 128 * 128 / 4; i += 256) {
            int r = i >> 5, c = i & 31;
            long idx = (long)(s0 + r) * rs4 + b * (TDIM / 4) + (e0 >> 2) + c;
            os[idx] = xs[idx];
        }
        return;
    }

    __shared__ unsigned short As[128 * FLDS];
    __shared__ unsigned short Bs[128 * FLDS];
    const float* __restrict__ Wb = W + (long)eb * TDIM * TDIM;

    const int lane = tid & 63;
    const int wave = tid >> 6;
    const int wrr  = wave >> 1;
    const int wcc  = wave & 1;

    f32x4 acc[4][4];
    #pragma unroll
    for (int m = 0; m < 4; ++m)
        #pragma unroll
        for (int n = 0; n < 4; ++n)
            acc[m][n] = (f32x4){0.f, 0.f, 0.f, 0.f};

    const int rg = tid >> 3;
    const int cg = tid & 7;
    const int fr = lane & 15;
    const int fo = (lane >> 4) * 8;

    for (int k0 = 0; k0 < TDIM; k0 += 32) {
        __syncthreads();
        #pragma unroll
        for (int pp = 0; pp < 4; ++pp) {
            const int r = rg + pp * 32;
            f32x4 av = *(const f32x4*)(x  + (long)(s0 + r) * (TBZ * TDIM) + b * TDIM + k0 + cg * 4);
            f32x4 bv = *(const f32x4*)(Wb + (long)(e0 + r) * TDIM + k0 + cg * 4);
            unsigned int alo = (unsigned)f2bf(av.x) | ((unsigned)f2bf(av.y) << 16);
            unsigned int ahi = (unsigned)f2bf(av.z) | ((unsigned)f2bf(av.w) << 16);
            unsigned int blo = (unsigned)f2bf(bv.x) | ((unsigned)f2bf(bv.y) << 16);
            unsigned int bhi = (unsigned)f2bf(bv.z) | ((unsigned)f2bf(bv.w) << 16);
            *(uint2*)&As[r * FLDS + cg * 4] = make_uint2(alo, ahi);
            *(uint2*)&Bs[r * FLDS + cg * 4] = make_uint2(blo, bhi);
        }
        __syncthreads();

        bf16x8 af2[4], bfm[4];
        #pragma unroll
        for (int m = 0; m < 4; ++m)
            af2[m] = *(const bf16x8*)&As[(wrr * 64 + m * 16 + fr) * FLDS + fo];
        #pragma unroll
        for (int n = 0; n < 4; ++n)
            bfm[n] = *(const bf16x8*)&Bs[(wcc * 64 + n * 16 + fr) * FLDS + fo];
        #pragma unroll
        for (int m = 0; m < 4; ++m)
            #pragma unroll
            for (int n = 0; n < 4; ++n)
                acc[m][n] = __builtin_amdgcn_mfma_f32_16x16x32_bf16(af2[m], bfm[n], acc[m][n], 0, 0, 0);
    }

    const int cr = lane >> 4;
    const int cc2 = lane & 15;
    #pragma unroll
    for (int n = 0; n < 4; ++n) {
        const int e  = e0 + wcc * 64 + n * 16 + cc2;
        const float bv = bias[eb * TDIM + e];
        #pragma unroll
        for (int m = 0; m < 4; ++m) {
            #pragma unroll
            for (int j = 0; j < 4; ++j) {
                const int s = s0 + wrr * 64 + m * 16 + cr * 4 + j;
                out[(long)s * (TBZ * TDIM) + b * TDIM + e] = acc[m][n][j] + bv;
            }
        }
    }
}

extern "C" void kernel_launch(void* const* d_in, const int* in_sizes, int n_in,
                              void* d_out, int out_size, void* d_ws, size_t ws_size,
                              hipStream_t stream) {
    const float* x        = (const float*)d_in[0];
    const int*   lang_ids = (const int*)d_in[1];
    const float* W        = (const float*)d_in[2];
    const float* bias     = (const float*)d_in[3];
    float*       out      = (float*)d_out;

    const size_t xbytes = (size_t)TSEQ * TBZ * TDIM * 2;   // 128 MiB
    const size_t wbytes = (size_t)NLS * TDIM * TDIM * 2;   // 16 MiB

    if (ws_size >= xbytes + wbytes) {
        unsigned short* xbp = (unsigned short*)d_ws;
        unsigned short* wbp = (unsigned short*)((char*)d_ws + xbytes);
        conv_all<<<2304, 256, 0, stream>>>(x, lang_ids, W, xbp, wbp, out);
        mapper_gemm8p<<<256, 512, 0, stream>>>(xbp, lang_ids, wbp, bias, out);
    } else {
        mapper_fused<<<TBZ * 16 * 8, 256, 0, stream>>>(x, lang_ids, W, bias, out);
    }
}